// Round 1
// baseline (402.089 us; speedup 1.0000x reference)
//
#include <hip/hip_runtime.h>

#define N_USER 100000
#define N_ITEM 50000
#define E_R    500000
#define E_T    250000
#define NB     (1 << 20)       // histogram bins
#define NCH    4096            // chunks of 256 bins
#define ZMIN   (-4.0f)
#define ZSCALE ((float)NB / 8.0f)

struct Acc {
  double sum_att;    // sum (boun3 - att + eps)^2
  double sum_trust;  // sum (label - p + eps)^2
  double C;          // concordant pair count (with 0.5*tie model)
  double S_ap;       // sum of precisions at positives
};

__device__ __forceinline__ float sigmoidf(float z) {
  return 1.0f / (1.0f + expf(-z));
}

__device__ __forceinline__ float wave_sum(float v) {
#pragma unroll
  for (int off = 32; off > 0; off >>= 1) v += __shfl_xor(v, off, 64);
  return v;
}

// ---------------- K1: collapse the linear chains into per-feature vectors ----
// wts[0..256)   = W4@W5@W6            (influ weight per concat-feature)
// wts[256]      = b4@W5@W6 + b5@W6 + b6
// wts[257..385) = W_so@W_so2          (trust weight per concat-feature)
// wts[385]      = b_so@W_so2 + b_so2
__global__ void k_collapse(const float* __restrict__ W4w, const float* __restrict__ W4b,
                           const float* __restrict__ W5w, const float* __restrict__ W5b,
                           const float* __restrict__ W6w, const float* __restrict__ W6b,
                           const float* __restrict__ Wsow, const float* __restrict__ Wsob,
                           const float* __restrict__ Wso2w, const float* __restrict__ Wso2b,
                           float* __restrict__ wts) {
  __shared__ float v56[128];
  int t = threadIdx.x;
  if (t < 128) {
    float s = 0.f;
    for (int k = 0; k < 64; ++k) s += W5w[t * 64 + k] * W6w[k];
    v56[t] = s;
  }
  __syncthreads();
  {
    float s = 0.f;
    for (int j = 0; j < 128; ++j) s += W4w[t * 128 + j] * v56[j];
    wts[t] = s;
  }
  if (t < 128) {
    float s = 0.f;
    for (int k = 0; k < 64; ++k) s += Wsow[t * 64 + k] * Wso2w[k];
    wts[257 + t] = s;
  }
  if (t == 0) {
    float b = W6b[0];
    for (int k = 0; k < 64; ++k) b += W5b[k] * W6w[k];
    for (int j = 0; j < 128; ++j) b += W4b[j] * v56[j];
    wts[256] = b;
    float bs = Wso2b[0];
    for (int k = 0; k < 64; ++k) bs += Wsob[k] * Wso2w[k];
    wts[385] = bs;
  }
}

// ---------------- K2: per-user scalars (wave per node, lane = feature dim) ---
__global__ void k_users(const float* __restrict__ xu, const float* __restrict__ ui,
                        const float* __restrict__ au, const float* __restrict__ tt,
                        const float* __restrict__ Wattw, const float* __restrict__ wts,
                        float2* __restrict__ u_rate, float2* __restrict__ u_trust) {
  int lane = threadIdx.x & 63;
  int wave = blockIdx.x * (blockDim.x >> 6) + (threadIdx.x >> 6);
  int nw = gridDim.x * (blockDim.x >> 6);
  float we_x = wts[64 + lane];        // x_u slice of collapsed influ weight
  float we_u = wts[192 + lane];       // user_intent slice
  float wa   = Wattw[lane];           // a_u slice of W_att
  float w1   = wts[257 + lane];       // t-src slice of collapsed trust weight
  float w2   = wts[257 + 64 + lane];  // t-dst slice
  for (int u = wave; u < N_USER; u += nw) {
    int base = u * 64 + lane;
    float x = xu[base], uin = ui[base], a = au[base], tv = tt[base];
    float s0 = wave_sum(x * we_x + uin * we_u);
    float s1 = wave_sum(a * wa);
    float s2 = wave_sum(tv * w1);
    float s3 = wave_sum(tv * w2);
    if (lane == 0) {
      u_rate[u]  = make_float2(s0, s1);
      u_trust[u] = make_float2(s2, s3);
    }
  }
}

// ---------------- K3: per-item scalars ---------------------------------------
__global__ void k_items(const float* __restrict__ xi, const float* __restrict__ ii,
                        const float* __restrict__ ai, const float* __restrict__ Wattw,
                        const float* __restrict__ wts, float2* __restrict__ i_rate) {
  int lane = threadIdx.x & 63;
  int wave = blockIdx.x * (blockDim.x >> 6) + (threadIdx.x >> 6);
  int nw = gridDim.x * (blockDim.x >> 6);
  float we_i = wts[lane];        // item_intent slice
  float we_x = wts[128 + lane];  // x_i slice
  float wa   = Wattw[64 + lane]; // a_i slice of W_att
  for (int i = wave; i < N_ITEM; i += nw) {
    int base = i * 64 + lane;
    float x = xi[base], iin = ii[base], a = ai[base];
    float s0 = wave_sum(iin * we_i + x * we_x);
    float s1 = wave_sum(a * wa);
    if (lane == 0) i_rate[i] = make_float2(s0, s1);
  }
}

// ---------------- K4: rated edges: pos_score + l_att partial -----------------
__global__ void k_rated(const int* __restrict__ src, const int* __restrict__ dst,
                        const float* __restrict__ boun3,
                        const float2* __restrict__ u_rate, const float2* __restrict__ i_rate,
                        const float* __restrict__ wts, const float* __restrict__ Wattb,
                        float* __restrict__ out, Acc* __restrict__ acc) {
  float batt = Wattb[0];
  float beff = wts[256];
  float local = 0.f;
  for (int e = blockIdx.x * blockDim.x + threadIdx.x; e < E_R; e += gridDim.x * blockDim.x) {
    int s = src[e], d = dst[e];
    float2 ur = u_rate[s];
    float2 ir = i_rate[d];
    out[e] = ur.x + ir.x + beff;  // pos_score == influ (score term is +-0.0)
    float att = sigmoidf(ur.y + ir.y + batt);
    float dis = boun3[e] - att + 1e-10f;
    local += dis * dis;
  }
  float w = wave_sum(local);
  __shared__ double sd[4];
  if ((threadIdx.x & 63) == 0) sd[threadIdx.x >> 6] = (double)w;
  __syncthreads();
  if (threadIdx.x == 0) atomicAdd(&acc->sum_att, sd[0] + sd[1] + sd[2] + sd[3]);
}

// ---------------- K5: trust edges: loss partial + score histogram ------------
__global__ void k_trust(const int* __restrict__ tps, const int* __restrict__ tpd,
                        const int* __restrict__ tns, const int* __restrict__ tnd,
                        const float2* __restrict__ u_trust, const float* __restrict__ wts,
                        unsigned* __restrict__ histP, unsigned* __restrict__ histN,
                        Acc* __restrict__ acc) {
  float bso = wts[385];
  float local = 0.f;
  const int total = 2 * E_T;
  for (int e = blockIdx.x * blockDim.x + threadIdx.x; e < total; e += gridDim.x * blockDim.x) {
    int s, d, lab;
    if (e < E_T) { s = tps[e]; d = tpd[e]; lab = 1; }
    else         { s = tns[e - E_T]; d = tnd[e - E_T]; lab = 0; }
    float z = u_trust[s].x + u_trust[d].y + bso;  // logit; monotone with sigmoid
    float p = sigmoidf(z);
    float dis = (lab ? (1.0f - p) : (-p)) + 1e-10f;
    local += dis * dis;
    int bin = (int)((z - ZMIN) * ZSCALE);
    bin = bin < 0 ? 0 : (bin >= NB ? NB - 1 : bin);
    atomicAdd(lab ? &histP[bin] : &histN[bin], 1u);
  }
  float w = wave_sum(local);
  __shared__ double sd[4];
  if ((threadIdx.x & 63) == 0) sd[threadIdx.x >> 6] = (double)w;
  __syncthreads();
  if (threadIdx.x == 0) atomicAdd(&acc->sum_trust, sd[0] + sd[1] + sd[2] + sd[3]);
}

// ---------------- K6: per-chunk (256-bin) sums -------------------------------
__global__ void k_chunksum(const unsigned* __restrict__ histP, const unsigned* __restrict__ histN,
                           unsigned* __restrict__ chP, unsigned* __restrict__ chN) {
  __shared__ unsigned sp[256], sn[256];
  int t = threadIdx.x;
  int bin = blockIdx.x * 256 + t;
  sp[t] = histP[bin];
  sn[t] = histN[bin];
  __syncthreads();
  for (int off = 128; off > 0; off >>= 1) {
    if (t < off) { sp[t] += sp[t + off]; sn[t] += sn[t + off]; }
    __syncthreads();
  }
  if (t == 0) { chP[blockIdx.x] = sp[0]; chN[blockIdx.x] = sn[0]; }
}

// ---------------- K7: exclusive scan over the 4096 chunk sums ----------------
__global__ void k_scan(const unsigned* __restrict__ chP, const unsigned* __restrict__ chN,
                       unsigned* __restrict__ prefP, unsigned* __restrict__ prefN) {
  __shared__ unsigned shp[1024], shn[1024];
  int t = threadIdx.x;
  int base = t * 4;
  unsigned ep[4], en[4], runp = 0, runn = 0;
#pragma unroll
  for (int i = 0; i < 4; ++i) {
    ep[i] = runp; en[i] = runn;
    runp += chP[base + i]; runn += chN[base + i];
  }
  shp[t] = runp; shn[t] = runn;
  __syncthreads();
  for (int off = 1; off < 1024; off <<= 1) {
    unsigned ap_ = 0, an_ = 0;
    if (t >= off) { ap_ = shp[t - off]; an_ = shn[t - off]; }
    __syncthreads();
    shp[t] += ap_; shn[t] += an_;
    __syncthreads();
  }
  unsigned exP = shp[t] - runp, exN = shn[t] - runn;
#pragma unroll
  for (int i = 0; i < 4; ++i) {
    prefP[base + i] = exP + ep[i];
    prefN[base + i] = exN + en[i];
  }
}

// ---------------- K8: per-bin AUC / AP contributions -------------------------
__global__ void k_aucap(const unsigned* __restrict__ histP, const unsigned* __restrict__ histN,
                        const unsigned* __restrict__ prefP, const unsigned* __restrict__ prefN,
                        Acc* __restrict__ acc) {
  __shared__ unsigned sp[256], sn[256];
  int t = threadIdx.x;
  int bin = blockIdx.x * 256 + t;
  unsigned np = histP[bin], nn = histN[bin];
  sp[t] = np; sn[t] = nn;
  __syncthreads();
  for (int off = 1; off < 256; off <<= 1) {
    unsigned ap_ = 0, an_ = 0;
    if (t >= off) { ap_ = sp[t - off]; an_ = sn[t - off]; }
    __syncthreads();
    sp[t] += ap_; sn[t] += an_;
    __syncthreads();
  }
  unsigned PA = prefP[blockIdx.x] + sp[t] - np;  // #pos in strictly lower bins
  unsigned NA = prefN[blockIdx.x] + sn[t] - nn;  // #neg in strictly lower bins
  double Cc = (double)np * (double)NA + 0.5 * (double)np * (double)nn;
  double apc = 0.0;
  if (np > 0) {
    double cpa = (double)(E_T - PA - np);  // pos in strictly higher bins (earlier in desc order)
    double cna = (double)(E_T - NA - nn);
    double ratio = (double)(np + nn) / (double)np;
    for (unsigned j = 1; j <= np; ++j) {
      double r = ((double)j - 0.5) * ratio + 0.5;  // modeled local rank of j-th pos
      apc += (cpa + (double)j) / (cpa + cna + r);
    }
  }
  __shared__ double dc[256], da[256];
  dc[t] = Cc; da[t] = apc;
  __syncthreads();
  for (int off = 128; off > 0; off >>= 1) {
    if (t < off) { dc[t] += dc[t + off]; da[t] += da[t + off]; }
    __syncthreads();
  }
  if (t == 0) {
    atomicAdd(&acc->C, dc[0]);
    atomicAdd(&acc->S_ap, da[0]);
  }
}

// ---------------- K9: finalize scalars ---------------------------------------
__global__ void k_finalize(const Acc* __restrict__ acc, float* __restrict__ out) {
  if (threadIdx.x == 0 && blockIdx.x == 0) {
    out[E_R + 0] = (float)sqrt(acc->sum_att / (double)E_R);                    // l_att
    out[E_R + 1] = (float)(acc->C / ((double)E_T * (double)E_T));              // auc
    out[E_R + 2] = (float)(acc->S_ap / (double)E_T);                           // ap
    out[E_R + 3] = (float)sqrt(acc->sum_trust / (double)(2 * E_T));            // loss_trust
  }
}

extern "C" void kernel_launch(void* const* d_in, const int* in_sizes, int n_in,
                              void* d_out, int out_size, void* d_ws, size_t ws_size,
                              hipStream_t stream) {
  (void)in_sizes; (void)n_in; (void)out_size; (void)ws_size;
  const float* x_u        = (const float*)d_in[0];
  const float* x_i        = (const float*)d_in[1];
  const float* a_u        = (const float*)d_in[2];
  const float* a_i        = (const float*)d_in[3];
  const float* t          = (const float*)d_in[4];
  const float* boun3      = (const float*)d_in[5];
  const float* user_int   = (const float*)d_in[6];
  const float* item_int   = (const float*)d_in[7];
  const float* W_att_w    = (const float*)d_in[8];
  const float* W_att_b    = (const float*)d_in[9];
  const float* W4_w       = (const float*)d_in[10];
  const float* W4_b       = (const float*)d_in[11];
  const float* W5_w       = (const float*)d_in[12];
  const float* W5_b       = (const float*)d_in[13];
  const float* W6_w       = (const float*)d_in[14];
  const float* W6_b       = (const float*)d_in[15];
  const float* W_so_w     = (const float*)d_in[16];
  const float* W_so_b     = (const float*)d_in[17];
  const float* W_so2_w    = (const float*)d_in[18];
  const float* W_so2_b    = (const float*)d_in[19];
  const int*   rated_src  = (const int*)d_in[20];
  const int*   rated_dst  = (const int*)d_in[21];
  const int*   tp_src     = (const int*)d_in[22];
  const int*   tp_dst     = (const int*)d_in[23];
  const int*   tn_src     = (const int*)d_in[24];
  const int*   tn_dst     = (const int*)d_in[25];
  float* out = (float*)d_out;

  // workspace layout
  char* ws = (char*)d_ws;
  Acc* acc = (Acc*)ws;                                  // 64 B reserved
  unsigned* histP = (unsigned*)(ws + 64);               // 4 MB
  unsigned* histN = histP + NB;                         // 4 MB
  unsigned* chP   = histN + NB;                         // 16 KB each
  unsigned* chN   = chP + NCH;
  unsigned* prefP = chN + NCH;
  unsigned* prefN = prefP + NCH;
  float* wts      = (float*)(prefN + NCH);              // 512 floats reserved
  float2* u_rate  = (float2*)(wts + 512);               // {s_user, att_u}
  float2* u_trust = u_rate + N_USER;                    // {ts_src, ts_dst}
  float2* i_rate  = u_trust + N_USER;                   // {s_item, att_i}

  // zero accumulators + histograms (ws is poisoned before every launch)
  hipMemsetAsync(ws, 0, 64 + (size_t)2 * NB * sizeof(unsigned), stream);

  k_collapse<<<1, 256, 0, stream>>>(W4_w, W4_b, W5_w, W5_b, W6_w, W6_b,
                                    W_so_w, W_so_b, W_so2_w, W_so2_b, wts);
  k_users<<<1024, 256, 0, stream>>>(x_u, user_int, a_u, t, W_att_w, wts, u_rate, u_trust);
  k_items<<<512, 256, 0, stream>>>(x_i, item_int, a_i, W_att_w, wts, i_rate);
  k_rated<<<1024, 256, 0, stream>>>(rated_src, rated_dst, boun3, u_rate, i_rate,
                                    wts, W_att_b, out, acc);
  k_trust<<<1024, 256, 0, stream>>>(tp_src, tp_dst, tn_src, tn_dst, u_trust, wts,
                                    histP, histN, acc);
  k_chunksum<<<NCH, 256, 0, stream>>>(histP, histN, chP, chN);
  k_scan<<<1, 1024, 0, stream>>>(chP, chN, prefP, prefN);
  k_aucap<<<NCH, 256, 0, stream>>>(histP, histN, prefP, prefN, acc);
  k_finalize<<<1, 64, 0, stream>>>(acc, out);
}

// Round 2
// 275.825 us; speedup vs baseline: 1.4578x; 1.4578x over previous
//
#include <hip/hip_runtime.h>

#define N_USER 100000
#define N_ITEM 50000
#define E_R    500000
#define E_T    250000
#define NB     (1 << 20)       // histogram bins
#define NCH    4096            // chunks of 256 bins
#define ZMIN   (-4.0f)
#define ZSCALE ((float)NB / 8.0f)

__device__ __forceinline__ float sigmoidf(float z) {
  return 1.0f / (1.0f + expf(-z));
}

__device__ __forceinline__ float wave_sum_f(float v) {
#pragma unroll
  for (int off = 32; off > 0; off >>= 1) v += __shfl_xor(v, off, 64);
  return v;
}

__device__ __forceinline__ double wave_sum_d(double v) {
#pragma unroll
  for (int off = 32; off > 0; off >>= 1) v += __shfl_xor(v, off, 64);
  return v;
}

// ---------------- K1: collapse the affine chains into per-feature vectors ---
// wts[0..256)   = W4@W5@W6            wts[256]  = b4@W5@W6 + b5@W6 + b6
// wts[257..385) = W_so@W_so2          wts[385]  = b_so@W_so2 + b_so2
__global__ void k_collapse(const float* __restrict__ W4w, const float* __restrict__ W4b,
                           const float* __restrict__ W5w, const float* __restrict__ W5b,
                           const float* __restrict__ W6w, const float* __restrict__ W6b,
                           const float* __restrict__ Wsow, const float* __restrict__ Wsob,
                           const float* __restrict__ Wso2w, const float* __restrict__ Wso2b,
                           float* __restrict__ wts) {
  __shared__ float v56[128];
  int t = threadIdx.x;
  if (t < 128) {
    float s = 0.f;
    for (int k = 0; k < 64; ++k) s += W5w[t * 64 + k] * W6w[k];
    v56[t] = s;
  }
  __syncthreads();
  {
    float s = 0.f;
    for (int j = 0; j < 128; ++j) s += W4w[t * 128 + j] * v56[j];
    wts[t] = s;
  }
  if (t < 128) {
    float s = 0.f;
    for (int k = 0; k < 64; ++k) s += Wsow[t * 64 + k] * Wso2w[k];
    wts[257 + t] = s;
  }
  // biases via wave 0 (parallel, no serial 192-iter loop)
  if (t < 64) {
    float pb = W5b[t] * W6w[t] + W4b[t] * v56[t] + W4b[64 + t] * v56[64 + t];
    float ps = Wsob[t] * Wso2w[t];
    pb = wave_sum_f(pb);
    ps = wave_sum_f(ps);
    if (t == 0) {
      wts[256] = pb + W6b[0];
      wts[385] = ps + Wso2b[0];
    }
  }
}

// ---------------- K2: per-node scalars (wave per node, lane = feature dim) --
// blocks [0,1024): users; [1024,1536): items
__global__ void k_nodes(const float* __restrict__ xu, const float* __restrict__ ui,
                        const float* __restrict__ au, const float* __restrict__ tt,
                        const float* __restrict__ xi, const float* __restrict__ ii,
                        const float* __restrict__ ai,
                        const float* __restrict__ Wattw, const float* __restrict__ wts,
                        float2* __restrict__ u_rate, float2* __restrict__ u_trust,
                        float2* __restrict__ i_rate) {
  int lane = threadIdx.x & 63;
  int wib = threadIdx.x >> 6;
  if (blockIdx.x < 1024) {
    int wave = blockIdx.x * 4 + wib;
    const int nw = 4096;
    float we_x = wts[64 + lane];
    float we_u = wts[192 + lane];
    float wa   = Wattw[lane];
    float w1   = wts[257 + lane];
    float w2   = wts[321 + lane];
    for (int u = wave; u < N_USER; u += nw) {
      int base = u * 64 + lane;
      float x = xu[base], uin = ui[base], a = au[base], tv = tt[base];
      float s0 = wave_sum_f(x * we_x + uin * we_u);
      float s1 = wave_sum_f(a * wa);
      float s2 = wave_sum_f(tv * w1);
      float s3 = wave_sum_f(tv * w2);
      if (lane == 0) {
        u_rate[u]  = make_float2(s0, s1);
        u_trust[u] = make_float2(s2, s3);
      }
    }
  } else {
    int wave = (blockIdx.x - 1024) * 4 + wib;
    const int nw = 2048;
    float we_i = wts[lane];
    float we_x = wts[128 + lane];
    float wa   = Wattw[64 + lane];
    for (int i = wave; i < N_ITEM; i += nw) {
      int base = i * 64 + lane;
      float x = xi[base], iin = ii[base], a = ai[base];
      float s0 = wave_sum_f(iin * we_i + x * we_x);
      float s1 = wave_sum_f(a * wa);
      if (lane == 0) i_rate[i] = make_float2(s0, s1);
    }
  }
}

// ---------------- K3: edges. blocks [0,1024): rated; [1024,2048): trust -----
__global__ void k_edges(const int* __restrict__ src, const int* __restrict__ dst,
                        const float* __restrict__ boun3,
                        const float2* __restrict__ u_rate, const float2* __restrict__ i_rate,
                        const int* __restrict__ tps, const int* __restrict__ tpd,
                        const int* __restrict__ tns, const int* __restrict__ tnd,
                        const float2* __restrict__ u_trust,
                        const float* __restrict__ wts, const float* __restrict__ Wattb,
                        float* __restrict__ out,
                        unsigned* __restrict__ histP, unsigned* __restrict__ histN,
                        double* __restrict__ partR, double* __restrict__ partT) {
  __shared__ double sd[4];
  float local = 0.f;
  if (blockIdx.x < 1024) {
    float batt = Wattb[0];
    float beff = wts[256];
    for (int e = blockIdx.x * 256 + threadIdx.x; e < E_R; e += 1024 * 256) {
      int s = src[e], d = dst[e];
      float2 ur = u_rate[s];
      float2 ir = i_rate[d];
      out[e] = ur.x + ir.x + beff;  // pos_score == influ (score term is +-0.0)
      float att = sigmoidf(ur.y + ir.y + batt);
      float dis = boun3[e] - att + 1e-10f;
      local += dis * dis;
    }
    float w = wave_sum_f(local);
    if ((threadIdx.x & 63) == 0) sd[threadIdx.x >> 6] = (double)w;
    __syncthreads();
    if (threadIdx.x == 0) partR[blockIdx.x] = sd[0] + sd[1] + sd[2] + sd[3];
  } else {
    float bso = wts[385];
    int b = blockIdx.x - 1024;
    for (int e = b * 256 + threadIdx.x; e < 2 * E_T; e += 1024 * 256) {
      int s, d, lab;
      if (e < E_T) { s = tps[e]; d = tpd[e]; lab = 1; }
      else         { s = tns[e - E_T]; d = tnd[e - E_T]; lab = 0; }
      float z = u_trust[s].x + u_trust[d].y + bso;  // logit; monotone with sigmoid
      float p = sigmoidf(z);
      float dis = (lab ? (1.0f - p) : (-p)) + 1e-10f;
      local += dis * dis;
      int bin = (int)((z - ZMIN) * ZSCALE);
      bin = bin < 0 ? 0 : (bin >= NB ? NB - 1 : bin);
      atomicAdd(lab ? &histP[bin] : &histN[bin], 1u);
    }
    float w = wave_sum_f(local);
    if ((threadIdx.x & 63) == 0) sd[threadIdx.x >> 6] = (double)w;
    __syncthreads();
    if (threadIdx.x == 0) partT[b] = sd[0] + sd[1] + sd[2] + sd[3];
  }
}

// ---------------- K4: per-chunk (256-bin) sums, wave per chunk --------------
__global__ void k_chunksum(const uint4* __restrict__ hP4, const uint4* __restrict__ hN4,
                           unsigned* __restrict__ chP, unsigned* __restrict__ chN) {
  int t = threadIdx.x, lane = t & 63, w = t >> 6;
  int chunk = blockIdx.x * 4 + w;
  int idx = chunk * 64 + lane;
  uint4 p = hP4[idx], n = hN4[idx];
  unsigned sp = p.x + p.y + p.z + p.w;
  unsigned sn = n.x + n.y + n.z + n.w;
#pragma unroll
  for (int off = 32; off > 0; off >>= 1) {
    sp += __shfl_xor(sp, off, 64);
    sn += __shfl_xor(sn, off, 64);
  }
  if (lane == 0) { chP[chunk] = sp; chN[chunk] = sn; }
}

// ---------------- K5: exclusive scan over the 4096 chunk sums ---------------
__global__ void k_scan(const unsigned* __restrict__ chP, const unsigned* __restrict__ chN,
                       unsigned* __restrict__ prefP, unsigned* __restrict__ prefN) {
  __shared__ unsigned shp[1024], shn[1024];
  int t = threadIdx.x;
  int base = t * 4;
  unsigned ep[4], en[4], runp = 0, runn = 0;
#pragma unroll
  for (int i = 0; i < 4; ++i) {
    ep[i] = runp; en[i] = runn;
    runp += chP[base + i]; runn += chN[base + i];
  }
  shp[t] = runp; shn[t] = runn;
  __syncthreads();
  for (int off = 1; off < 1024; off <<= 1) {
    unsigned ap_ = 0, an_ = 0;
    if (t >= off) { ap_ = shp[t - off]; an_ = shn[t - off]; }
    __syncthreads();
    shp[t] += ap_; shn[t] += an_;
    __syncthreads();
  }
  unsigned exP = shp[t] - runp, exN = shn[t] - runn;
#pragma unroll
  for (int i = 0; i < 4; ++i) {
    prefP[base + i] = exP + ep[i];
    prefN[base + i] = exN + en[i];
  }
}

// ---------------- K6: per-bin AUC / AP contributions → per-block partials ---
__global__ void k_aucap(const unsigned* __restrict__ histP, const unsigned* __restrict__ histN,
                        const unsigned* __restrict__ prefP, const unsigned* __restrict__ prefN,
                        double* __restrict__ partC, double* __restrict__ partA) {
  __shared__ unsigned sp[256], sn[256];
  int t = threadIdx.x;
  int bin = blockIdx.x * 256 + t;
  unsigned np = histP[bin], nn = histN[bin];
  sp[t] = np; sn[t] = nn;
  __syncthreads();
  for (int off = 1; off < 256; off <<= 1) {
    unsigned ap_ = 0, an_ = 0;
    if (t >= off) { ap_ = sp[t - off]; an_ = sn[t - off]; }
    __syncthreads();
    sp[t] += ap_; sn[t] += an_;
    __syncthreads();
  }
  unsigned PA = prefP[blockIdx.x] + sp[t] - np;  // #pos in strictly lower bins
  unsigned NA = prefN[blockIdx.x] + sn[t] - nn;  // #neg in strictly lower bins
  double Cc = (double)np * (double)NA + 0.5 * (double)np * (double)nn;
  double apc = 0.0;
  if (np > 0) {
    double cpa = (double)(E_T - PA - np);  // pos strictly higher (earlier in desc order)
    double cna = (double)(E_T - NA - nn);
    double ratio = (double)(np + nn) / (double)np;
    for (unsigned j = 1; j <= np; ++j) {
      double r = ((double)j - 0.5) * ratio + 0.5;  // modeled local rank of j-th pos
      apc += (cpa + (double)j) / (cpa + cna + r);
    }
  }
  double c = wave_sum_d(Cc);
  double a = wave_sum_d(apc);
  __shared__ double dc[4], da[4];
  int lane = t & 63, w = t >> 6;
  if (lane == 0) { dc[w] = c; da[w] = a; }
  __syncthreads();
  if (t == 0) {
    partC[blockIdx.x] = dc[0] + dc[1] + dc[2] + dc[3];
    partA[blockIdx.x] = da[0] + da[1] + da[2] + da[3];
  }
}

// ---------------- K7: final reduce + scalar outputs -------------------------
__global__ void k_final(const double* __restrict__ partR, const double* __restrict__ partT,
                        const double* __restrict__ partC, const double* __restrict__ partA,
                        float* __restrict__ out) {
  int t = threadIdx.x;
  double sR = 0, sT = 0, sC = 0, sA = 0;
  for (int i = t; i < 1024; i += 256) { sR += partR[i]; sT += partT[i]; }
  for (int i = t; i < 4096; i += 256) { sC += partC[i]; sA += partA[i]; }
  sR = wave_sum_d(sR); sT = wave_sum_d(sT);
  sC = wave_sum_d(sC); sA = wave_sum_d(sA);
  __shared__ double sh[4][4];
  int lane = t & 63, w = t >> 6;
  if (lane == 0) { sh[w][0] = sR; sh[w][1] = sT; sh[w][2] = sC; sh[w][3] = sA; }
  __syncthreads();
  if (t == 0) {
    double R = sh[0][0] + sh[1][0] + sh[2][0] + sh[3][0];
    double T = sh[0][1] + sh[1][1] + sh[2][1] + sh[3][1];
    double C = sh[0][2] + sh[1][2] + sh[2][2] + sh[3][2];
    double A = sh[0][3] + sh[1][3] + sh[2][3] + sh[3][3];
    out[E_R + 0] = (float)sqrt(R / (double)E_R);           // l_att
    out[E_R + 1] = (float)(C / ((double)E_T * (double)E_T));// auc
    out[E_R + 2] = (float)(A / (double)E_T);               // ap
    out[E_R + 3] = (float)sqrt(T / (double)(2 * E_T));     // loss_trust
  }
}

extern "C" void kernel_launch(void* const* d_in, const int* in_sizes, int n_in,
                              void* d_out, int out_size, void* d_ws, size_t ws_size,
                              hipStream_t stream) {
  (void)in_sizes; (void)n_in; (void)out_size; (void)ws_size;
  const float* x_u        = (const float*)d_in[0];
  const float* x_i        = (const float*)d_in[1];
  const float* a_u        = (const float*)d_in[2];
  const float* a_i        = (const float*)d_in[3];
  const float* t          = (const float*)d_in[4];
  const float* boun3      = (const float*)d_in[5];
  const float* user_int   = (const float*)d_in[6];
  const float* item_int   = (const float*)d_in[7];
  const float* W_att_w    = (const float*)d_in[8];
  const float* W_att_b    = (const float*)d_in[9];
  const float* W4_w       = (const float*)d_in[10];
  const float* W4_b       = (const float*)d_in[11];
  const float* W5_w       = (const float*)d_in[12];
  const float* W5_b       = (const float*)d_in[13];
  const float* W6_w       = (const float*)d_in[14];
  const float* W6_b       = (const float*)d_in[15];
  const float* W_so_w     = (const float*)d_in[16];
  const float* W_so_b     = (const float*)d_in[17];
  const float* W_so2_w    = (const float*)d_in[18];
  const float* W_so2_b    = (const float*)d_in[19];
  const int*   rated_src  = (const int*)d_in[20];
  const int*   rated_dst  = (const int*)d_in[21];
  const int*   tp_src     = (const int*)d_in[22];
  const int*   tp_dst     = (const int*)d_in[23];
  const int*   tn_src     = (const int*)d_in[24];
  const int*   tn_dst     = (const int*)d_in[25];
  float* out = (float*)d_out;

  // workspace layout (doubles first for alignment; all partials fully written)
  char* ws = (char*)d_ws;
  double* partR   = (double*)ws;                        // 1024
  double* partT   = partR + 1024;                       // 1024
  double* partC   = partT + 1024;                       // 4096
  double* partA   = partC + 4096;                       // 4096
  unsigned* histP = (unsigned*)(partA + 4096);          // 4 MB
  unsigned* histN = histP + NB;                         // 4 MB
  unsigned* chP   = histN + NB;                         // 16 KB each
  unsigned* chN   = chP + NCH;
  unsigned* prefP = chN + NCH;
  unsigned* prefN = prefP + NCH;
  float* wts      = (float*)(prefN + NCH);              // 512 floats reserved
  float2* u_rate  = (float2*)(wts + 512);               // {s_user, att_u}
  float2* u_trust = u_rate + N_USER;                    // {ts_src, ts_dst}
  float2* i_rate  = u_trust + N_USER;                   // {s_item, att_i}

  // zero only the histograms (everything else is fully written each call)
  hipMemsetAsync(histP, 0, (size_t)2 * NB * sizeof(unsigned), stream);

  k_collapse<<<1, 256, 0, stream>>>(W4_w, W4_b, W5_w, W5_b, W6_w, W6_b,
                                    W_so_w, W_so_b, W_so2_w, W_so2_b, wts);
  k_nodes<<<1536, 256, 0, stream>>>(x_u, user_int, a_u, t, x_i, item_int, a_i,
                                    W_att_w, wts, u_rate, u_trust, i_rate);
  k_edges<<<2048, 256, 0, stream>>>(rated_src, rated_dst, boun3, u_rate, i_rate,
                                    tp_src, tp_dst, tn_src, tn_dst, u_trust,
                                    wts, W_att_b, out, histP, histN, partR, partT);
  k_chunksum<<<1024, 256, 0, stream>>>((const uint4*)histP, (const uint4*)histN, chP, chN);
  k_scan<<<1, 1024, 0, stream>>>(chP, chN, prefP, prefN);
  k_aucap<<<NCH, 256, 0, stream>>>(histP, histN, prefP, prefN, partC, partA);
  k_final<<<1, 256, 0, stream>>>(partR, partT, partC, partA, out);
}